// Round 5
// baseline (466.103 us; speedup 1.0000x reference)
//
#include <hip/hip_runtime.h>
#include <stdint.h>

#define SEQ   2048
#define BATCH 4
#define NH    16
#define HD    64
#define DIMN  1024
#define MROWS (BATCH*SEQ)   // 8192

typedef __attribute__((ext_vector_type(8))) short          bf16x8;
typedef __attribute__((ext_vector_type(8))) unsigned short ushort8;
typedef __attribute__((ext_vector_type(4))) float          f32x4;

static __device__ __forceinline__ unsigned short f2bf(float f) {
    unsigned int u = __builtin_bit_cast(unsigned int, f);
    u += 0x7fffu + ((u >> 16) & 1u);          // RNE
    return (unsigned short)(u >> 16);
}
// RNE-ish (round-half-up) pack: 3 ops
static __device__ __forceinline__ unsigned int pack2bf(float lo, float hi) {
    unsigned int a = __builtin_bit_cast(unsigned int, lo) + 0x8000u;
    unsigned int b = __builtin_bit_cast(unsigned int, hi) + 0x8000u;
    return __builtin_amdgcn_perm(b, a, 0x07060302u);
}
// truncating pack: 1 op (P in [0,1], rel err <= 2^-8, fine for softmax weights)
static __device__ __forceinline__ unsigned int pack2bf_trunc(float lo, float hi) {
    return __builtin_amdgcn_perm(__builtin_bit_cast(unsigned int, hi),
                                 __builtin_bit_cast(unsigned int, lo), 0x07060302u);
}

// ---------------------------------------------------------------- fused prologue
__global__ __launch_bounds__(256) void prologue_kernel(
        const float* __restrict__ x,
        const float* __restrict__ qw, const float* __restrict__ kw,
        const float* __restrict__ vw, const float* __restrict__ ow,
        unsigned short* __restrict__ xb,
        unsigned short* __restrict__ wq, unsigned short* __restrict__ wk,
        unsigned short* __restrict__ wv, unsigned short* __restrict__ wo,
        float* __restrict__ cosT, float* __restrict__ sinT,
        const unsigned char* __restrict__ mask, unsigned long long* __restrict__ m64) {
    const int bx = blockIdx.x, tid = threadIdx.x;
    if (bx < 4096 + 2048) {
        const float* s; unsigned short* d; int i;
        if (bx < 4096) { s = x; d = xb; i = bx * 2048 + tid * 8; }
        else {
            int wb = bx - 4096;
            int wsel = wb >> 9;
            s = wsel == 0 ? qw : (wsel == 1 ? kw : (wsel == 2 ? vw : ow));
            d = wsel == 0 ? wq : (wsel == 1 ? wk : (wsel == 2 ? wv : wo));
            i = (wb & 511) * 2048 + tid * 8;
        }
        float4 a = *(const float4*)(s + i);
        float4 b = *(const float4*)(s + i + 4);
        ushort8 o;
        o[0]=f2bf(a.x); o[1]=f2bf(a.y); o[2]=f2bf(a.z); o[3]=f2bf(a.w);
        o[4]=f2bf(b.x); o[5]=f2bf(b.y); o[6]=f2bf(b.z); o[7]=f2bf(b.w);
        *(ushort8*)(d + i) = o;
    } else if (bx < 6400) {
        int idx = (bx - 6144) * 256 + tid;        // SEQ*32
        int s = idx >> 5, j = idx & 31;
        float t = (float)(2 * j) / 64.0f;
        float freq = 1.0f / powf(10000.0f, t);
        float ang  = (float)s * freq;
        cosT[idx] = cosf(ang);
        sinT[idx] = sinf(ang);
    } else {
        if (tid < 128) {
            int b = tid >> 5, kt = tid & 31;
            const unsigned char* p = mask + b * SEQ + kt * 64;
            unsigned long long v = 0;
            for (int j = 0; j < 64; j++) v |= (unsigned long long)(p[j] != 0) << j;
            m64[tid] = v;
        }
    }
}

// ---------------------------------------------------------------- fused Q,K,V^T GEMM
// v3: LDS double-buffer + early stage; ONE barrier per 32-step. Source/read
// chunk XOR swizzle keeps SQ_LDS_BANK_CONFLICT at 0 (rule 21: linear dest,
// pre-swizzled source, swizzled read).
__global__ __launch_bounds__(256) void gemm_qkvt(const unsigned short* __restrict__ X,
        const unsigned short* __restrict__ Wq, const unsigned short* __restrict__ Wk,
        const unsigned short* __restrict__ Wv,
        const float* __restrict__ bq, const float* __restrict__ bk, const float* __restrict__ bv,
        unsigned short* __restrict__ Qo, unsigned short* __restrict__ Ko, unsigned short* __restrict__ Vto,
        const float* __restrict__ cosT, const float* __restrict__ sinT) {
    __shared__ __align__(16) unsigned short As0[128 * 32];
    __shared__ __align__(16) unsigned short Bs0[128 * 32];
    __shared__ __align__(16) unsigned short As1[128 * 32];
    __shared__ __align__(16) unsigned short Bs1[128 * 32];
    const int which = blockIdx.x >> 3;
    const int tid  = threadIdx.x;
    const int wid  = tid >> 6, lane = tid & 63;
    const int quad = lane >> 4, l15 = lane & 15;
    const int wm   = wid >> 1,  wn  = wid & 1;

    const unsigned short *Ag, *Bg;
    int m0, n0;
    if (which < 2) {
        m0 = blockIdx.y * 128;                 // token rows
        n0 = (blockIdx.x & 7) * 128;           // embed cols
        Ag = X;  Bg = which == 0 ? Wq : Wk;
    } else {
        m0 = (blockIdx.x & 7) * 128;           // e rows
        n0 = blockIdx.y * 128;                 // token rows
        Ag = Wv; Bg = X;
    }

    f32x4 acc[4][4];
#pragma unroll
    for (int i = 0; i < 4; i++)
#pragma unroll
        for (int j = 0; j < 4; j++) acc[i][j] = (f32x4)0.0f;

    const int rb = wid * 32 + (lane >> 2);
    const int cb = (((lane & 3) ^ ((lane >> 3) & 3)) * 8);
    const int rq = (quad ^ ((l15 >> 1) & 3)) * 8;

#define GSTAGE(BA, BB, KK) do {                                                             \
    _Pragma("unroll")                                                                       \
    for (int i_ = 0; i_ < 2; i_++) {                                                        \
        const unsigned short* ga_ = Ag + (size_t)(m0 + rb + i_ * 16) * DIMN + (KK) + cb;    \
        __builtin_amdgcn_global_load_lds((const __attribute__((address_space(1))) void*)ga_,\
            (__attribute__((address_space(3))) void*)&BA[(wid * 32 + i_ * 16) * 32], 16, 0, 0);\
        const unsigned short* gb_ = Bg + (size_t)(n0 + rb + i_ * 16) * DIMN + (KK) + cb;    \
        __builtin_amdgcn_global_load_lds((const __attribute__((address_space(1))) void*)gb_,\
            (__attribute__((address_space(3))) void*)&BB[(wid * 32 + i_ * 16) * 32], 16, 0, 0);\
    } } while (0)

#define GCOMP(BA, BB) do {                                                                  \
    bf16x8 af_[4], bf_[4];                                                                  \
    _Pragma("unroll")                                                                       \
    for (int f_ = 0; f_ < 4; f_++) af_[f_] = *(const bf16x8*)&BA[(wm * 64 + f_ * 16 + l15) * 32 + rq]; \
    _Pragma("unroll")                                                                       \
    for (int f_ = 0; f_ < 4; f_++) bf_[f_] = *(const bf16x8*)&BB[(wn * 64 + f_ * 16 + l15) * 32 + rq]; \
    _Pragma("unroll")                                                                       \
    for (int fm_ = 0; fm_ < 4; fm_++)                                                       \
        _Pragma("unroll")                                                                   \
        for (int fn_ = 0; fn_ < 4; fn_++)                                                   \
            acc[fm_][fn_] = __builtin_amdgcn_mfma_f32_16x16x32_bf16(af_[fm_], bf_[fn_], acc[fm_][fn_], 0, 0, 0); \
    } while (0)

    GSTAGE(As0, Bs0, 0);
    for (int k0 = 0; k0 < DIMN; k0 += 64) {
        __syncthreads();                           // As0/Bs0 ready
        GSTAGE(As1, Bs1, k0 + 32);                 // issue next into other buffer
        GCOMP(As0, Bs0);
        __syncthreads();                           // As1/Bs1 ready
        if (k0 + 64 < DIMN) GSTAGE(As0, Bs0, k0 + 64);
        GCOMP(As1, Bs1);
    }

    if (which < 2) {                            // Q or K: +bias, scale, RoPE, [B,H,S,D]
        const float* bias   = which == 0 ? bq : bk;
        unsigned short* Out = which == 0 ? Qo : Ko;
        const float scale = which == 0 ? 0.18033688011112042f : 1.0f;  // 0.125*log2e
        float bv4[4];
#pragma unroll
        for (int fn = 0; fn < 4; fn++) bv4[fn] = bias[n0 + wn * 64 + fn * 16 + l15];
        const int h = (n0 >> 6) + wn;
#pragma unroll
        for (int fm = 0; fm < 4; fm++)
#pragma unroll
            for (int r = 0; r < 4; r++) {
                int mrow = m0 + wm * 64 + fm * 16 + quad * 4 + r;
                int b = mrow >> 11, s = mrow & (SEQ - 1);
                unsigned short* orow = Out + ((size_t)(b * NH + h) * SEQ + s) * HD;
                float v0 = (acc[fm][0][r] + bv4[0]) * scale;
                float v1 = (acc[fm][1][r] + bv4[1]) * scale;
                float v2 = (acc[fm][2][r] + bv4[2]) * scale;
                float v3 = (acc[fm][3][r] + bv4[3]) * scale;
                int d0 = l15, d1 = 16 + l15;
                float c0 = cosT[s * 32 + d0], s0 = sinT[s * 32 + d0];
                float c1 = cosT[s * 32 + d1], s1 = sinT[s * 32 + d1];
                orow[d0]      = f2bf(v0 * c0 - v2 * s0);
                orow[d0 + 32] = f2bf(v0 * s0 + v2 * c0);
                orow[d1]      = f2bf(v1 * c1 - v3 * s1);
                orow[d1 + 32] = f2bf(v1 * s1 + v3 * c1);
            }
    } else {                                    // V^T: [B,H,D,S]
        float4 bb[4];
#pragma unroll
        for (int fm = 0; fm < 4; fm++)
            bb[fm] = *(const float4*)&bv[m0 + wm * 64 + fm * 16 + quad * 4];
        const int b     = n0 >> 11;
        const int sbase = (n0 & (SEQ - 1)) + wn * 64 + l15;
#pragma unroll
        for (int fm = 0; fm < 4; fm++)
#pragma unroll
            for (int r = 0; r < 4; r++) {
                int e = m0 + wm * 64 + fm * 16 + quad * 4 + r;
                float bval = r == 0 ? bb[fm].x : (r == 1 ? bb[fm].y : (r == 2 ? bb[fm].z : bb[fm].w));
                unsigned short* row = Vto + ((size_t)(b * NH + (e >> 6)) * HD + (e & 63)) * SEQ + sbase;
#pragma unroll
                for (int fn = 0; fn < 4; fn++)
                    row[fn * 16] = f2bf(acc[fm][fn][r] + bval);
            }
    }
#undef GSTAGE
#undef GCOMP
}

// ---------------------------------------------------------------- output-proj GEMM (fp32 out)
// v3: same double-buffer + early stage as gemm_qkvt.
__global__ __launch_bounds__(256) void gemm_bt(const unsigned short* __restrict__ A,
                                               const unsigned short* __restrict__ W,
                                               const float* __restrict__ bias,
                                               float* __restrict__ out) {
    __shared__ __align__(16) unsigned short As0[128 * 32];
    __shared__ __align__(16) unsigned short Bs0[128 * 32];
    __shared__ __align__(16) unsigned short As1[128 * 32];
    __shared__ __align__(16) unsigned short Bs1[128 * 32];
    const int tid  = threadIdx.x;
    const int wid  = tid >> 6, lane = tid & 63;
    const int quad = lane >> 4, l15 = lane & 15;
    const int wm   = wid >> 1,  wn  = wid & 1;
    const int m0   = blockIdx.y * 128, n0 = blockIdx.x * 128;

    f32x4 acc[4][4];
#pragma unroll
    for (int i = 0; i < 4; i++)
#pragma unroll
        for (int j = 0; j < 4; j++) acc[i][j] = (f32x4)0.0f;

    const int rb = wid * 32 + (lane >> 2);
    const int cb = (((lane & 3) ^ ((lane >> 3) & 3)) * 8);
    const int rq = (quad ^ ((l15 >> 1) & 3)) * 8;

#define GSTAGE(BA, BB, KK) do {                                                             \
    _Pragma("unroll")                                                                       \
    for (int i_ = 0; i_ < 2; i_++) {                                                        \
        const unsigned short* ga_ = A + (size_t)(m0 + rb + i_ * 16) * DIMN + (KK) + cb;     \
        __builtin_amdgcn_global_load_lds((const __attribute__((address_space(1))) void*)ga_,\
            (__attribute__((address_space(3))) void*)&BA[(wid * 32 + i_ * 16) * 32], 16, 0, 0);\
        const unsigned short* gb_ = W + (size_t)(n0 + rb + i_ * 16) * DIMN + (KK) + cb;     \
        __builtin_amdgcn_global_load_lds((const __attribute__((address_space(1))) void*)gb_,\
            (__attribute__((address_space(3))) void*)&BB[(wid * 32 + i_ * 16) * 32], 16, 0, 0);\
    } } while (0)

#define GCOMP(BA, BB) do {                                                                  \
    bf16x8 af_[4], bf_[4];                                                                  \
    _Pragma("unroll")                                                                       \
    for (int f_ = 0; f_ < 4; f_++) af_[f_] = *(const bf16x8*)&BA[(wm * 64 + f_ * 16 + l15) * 32 + rq]; \
    _Pragma("unroll")                                                                       \
    for (int f_ = 0; f_ < 4; f_++) bf_[f_] = *(const bf16x8*)&BB[(wn * 64 + f_ * 16 + l15) * 32 + rq]; \
    _Pragma("unroll")                                                                       \
    for (int fm_ = 0; fm_ < 4; fm_++)                                                       \
        _Pragma("unroll")                                                                   \
        for (int fn_ = 0; fn_ < 4; fn_++)                                                   \
            acc[fm_][fn_] = __builtin_amdgcn_mfma_f32_16x16x32_bf16(af_[fm_], bf_[fn_], acc[fm_][fn_], 0, 0, 0); \
    } while (0)

    GSTAGE(As0, Bs0, 0);
    for (int k0 = 0; k0 < DIMN; k0 += 64) {
        __syncthreads();
        GSTAGE(As1, Bs1, k0 + 32);
        GCOMP(As0, Bs0);
        __syncthreads();
        if (k0 + 64 < DIMN) GSTAGE(As0, Bs0, k0 + 64);
        GCOMP(As1, Bs1);
    }

    float bv4[4];
#pragma unroll
    for (int fn = 0; fn < 4; fn++) bv4[fn] = bias[n0 + wn * 64 + fn * 16 + l15];
#pragma unroll
    for (int fm = 0; fm < 4; fm++)
#pragma unroll
        for (int r = 0; r < 4; r++) {
            int mrow = m0 + wm * 64 + fm * 16 + quad * 4 + r;
            float* orow = out + (size_t)mrow * DIMN + n0 + wn * 64;
#pragma unroll
            for (int fn = 0; fn < 4; fn++) orow[fn * 16 + l15] = acc[fm][fn][r] + bv4[fn];
        }
#undef GSTAGE
#undef GCOMP
}

// ---------------------------------------------------------------- flash attention v12
// v9/v11 post-mortem: neither barrier structure moved the clock -> the cost
// was never the vmcnt drain. Pipe arithmetic: K/V fragment ds_reads alone are
// ~61us of DS-pipe demand, and the per-tile barrier phase-locks all 16 waves
// so DS/VALU/MFMA bursts alternate instead of overlapping.
// v12: NO LDS staging, NO barriers. K+V per (b,h) = 512 KB; XCD swizzle puts
// 8 (b,h) groups = 4 MB on each XCD's private L2, and the 16 q-blocks of a
// (b,h) re-read it from L2/L1 (Common-mistake #7: don't stage cache-fit
// data). Fragments load global->VGPR, software-pipelined by role at
// half-tile granularity: V(m) issued before QK(m) (consumed after softmax),
// K(m+1) issued right after QK(m) (consumed next half) -> compiler-counted
// vmcnt gives each batch a ~500-cycle completion window. Waves free-run:
// VMEM, DS (P round-trip only), VALU, MFMA overlap across drifted waves.
// LDS = 4.5 KiB Ps only. VGPR ~115 (spill tripwire: WRITE_SIZE >> 20 MB).
#define PSTRIDE 36
__global__ __launch_bounds__(256, 4) void attn_kernel(const unsigned short* __restrict__ Q,
                                                      const unsigned short* __restrict__ K,
                                                      const unsigned short* __restrict__ Vt,
                                                      const unsigned long long* __restrict__ M64,
                                                      unsigned short* __restrict__ Ob) {
    __shared__ __align__(16) unsigned short Ps[4 * 16 * PSTRIDE]; // 4.5 KiB wave-private

    const int tid  = threadIdx.x;
    const int wid  = tid >> 6, lane = tid & 63;
    const int quad = lane >> 4, l15 = lane & 15;
    // XCD-aware swizzle: xcd = bid&7; each XCD owns 8 complete (b,h) groups
    // -> K/V (4 MB) resident in that XCD's private L2.
    const int bid = blockIdx.x;
    const int bh  = (bid & 7) * 8 + (bid >> 7);
    const int qt  = (bid >> 3) & 15;
    const int b = bh >> 4, h = bh & 15;
    const int q0 = qt * 128;

    // persistent Q fragments: q = q0 + wid*32 + n*16 + l15
    bf16x8 qf[2][2];
#pragma unroll
    for (int n = 0; n < 2; n++) {
        const int qs = q0 + wid * 32 + n * 16 + l15;
#pragma unroll
        for (int dk = 0; dk < 2; dk++)
            qf[n][dk] = __builtin_bit_cast(bf16x8,
                *(const uint4*)&Q[((size_t)bh * SEQ + qs) * HD + dk * 32 + quad * 8]);
    }

    f32x4 Oa[4][2];                      // O^T: [df][n]; lane: d=df*16+quad*4+r, q=n*16+l15
#pragma unroll
    for (int i = 0; i < 4; i++)
#pragma unroll
        for (int n = 0; n < 2; n++) Oa[i][n] = (f32x4)0.0f;
    float ls[2] = {0.0f, 0.0f};

    unsigned short* Pw = &Ps[wid * 16 * PSTRIDE];
    const unsigned long long* Mrow = M64 + b * (SEQ / 64);

    const unsigned short* Kg = K + (size_t)bh * SEQ * HD;    // [S][D]
    const unsigned short* Vg = Vt + (size_t)bh * HD * SEQ;   // [D][S]

    // rolling per-lane fragment bases
    // K frag (half m): row = m*32 + f2*16 + l15, col = dk*32 + quad*8
    const unsigned short* pKn = Kg + (size_t)l15 * HD + quad * 8;
    // V frag (half m): row = df*16 + l15,        col = m*32 + quad*8
    const unsigned short* pVm = Vg + (size_t)l15 * SEQ + quad * 8;

    bf16x8 kf[2][2];
    // prologue: K fragments for half 0
#pragma unroll
    for (int f2 = 0; f2 < 2; f2++)
#pragma unroll
        for (int dk = 0; dk < 2; dk++)
            kf[f2][dk] = __builtin_bit_cast(bf16x8,
                *(const uint4*)(pKn + f2 * 16 * HD + dk * 32));
    pKn += 32 * HD;

    for (int kt = 0; kt < SEQ / 64; kt++) {
        unsigned long long mb = Mrow[kt];
#pragma unroll
        for (int h2 = 0; h2 < 2; h2++) {          // half index m = kt*2+h2
            // V fragments for this half (first use is PV, after softmax)
            bf16x8 vf[4];
#pragma unroll
            for (int df = 0; df < 4; df++)
                vf[df] = __builtin_bit_cast(bf16x8,
                    *(const uint4*)(pVm + (size_t)df * 16 * SEQ));
            pVm += 32;

            f32x4 st[2][2];
            __builtin_amdgcn_s_setprio(1);
#pragma unroll
            for (int f2 = 0; f2 < 2; f2++)
#pragma unroll
                for (int n = 0; n < 2; n++) {
                    st[f2][n] = __builtin_amdgcn_mfma_f32_16x16x32_bf16(kf[f2][0], qf[n][0], (f32x4)0.0f, 0, 0, 0);
                    st[f2][n] = __builtin_amdgcn_mfma_f32_16x16x32_bf16(kf[f2][1], qf[n][1], st[f2][n], 0, 0, 0);
                }
            __builtin_amdgcn_s_setprio(0);

            // prefetch K fragments for next half into the (now consumed) kf
            // regs; they fly under softmax+PV. Final iteration reads 8 KB
            // past this bh's K (next bh / Vtb region) -- mapped workspace,
            // value unused.
#pragma unroll
            for (int f2 = 0; f2 < 2; f2++)
#pragma unroll
                for (int dk = 0; dk < 2; dk++)
                    kf[f2][dk] = __builtin_bit_cast(bf16x8,
                        *(const uint4*)(pKn + f2 * 16 * HD + dk * 32));
            pKn += 32 * HD;

            unsigned int mh = (unsigned int)(mb >> (h2 * 32));
            if (mh) {                         // wave-uniform; rare
#pragma unroll
                for (int f2 = 0; f2 < 2; f2++)
#pragma unroll
                    for (int n = 0; n < 2; n++)
#pragma unroll
                        for (int r = 0; r < 4; r++) {
                            int kk = f2 * 16 + quad * 4 + r;
                            if ((mh >> kk) & 1u) st[f2][n][r] = -1e9f;
                        }
            }

            // raw v_exp_f32, sum, pack, wave-private P round-trip through the
            // SAME 16 rows per n (DS pipe in-order per wave -> no barrier).
            // 18-dword rows: 18*l15 mod 32 covers 16 distinct even banks, +1
            // odd neighbor per b64 -> all 32 banks, conflict-free.
#pragma unroll
            for (int n = 0; n < 2; n++) {
#pragma unroll
                for (int f2 = 0; f2 < 2; f2++) {
                    float p0 = __builtin_amdgcn_exp2f(st[f2][n][0]);
                    float p1 = __builtin_amdgcn_exp2f(st[f2][n][1]);
                    float p2 = __builtin_amdgcn_exp2f(st[f2][n][2]);
                    float p3 = __builtin_amdgcn_exp2f(st[f2][n][3]);
                    ls[n] += (p0 + p1) + (p2 + p3);
                    uint2 w;
                    w.x = pack2bf_trunc(p0, p1);
                    w.y = pack2bf_trunc(p2, p3);
                    *(uint2*)&Pw[l15 * PSTRIDE + f2 * 16 + quad * 4] = w;
                }
                uint2 plo = *(const uint2*)&Pw[l15 * PSTRIDE + quad * 8];
                uint2 phi = *(const uint2*)&Pw[l15 * PSTRIDE + quad * 8 + 4];
                uint4 pw4;
                pw4.x = plo.x; pw4.y = plo.y; pw4.z = phi.x; pw4.w = phi.y;
                bf16x8 pf = __builtin_bit_cast(bf16x8, pw4);
                __builtin_amdgcn_s_setprio(1);
#pragma unroll
                for (int df = 0; df < 4; df++)
                    Oa[df][n] = __builtin_amdgcn_mfma_f32_16x16x32_bf16(vf[df], pf, Oa[df][n], 0, 0, 0);
                __builtin_amdgcn_s_setprio(0);
            }
        }
    }

    float linv[2];
#pragma unroll
    for (int n = 0; n < 2; n++) {
        float l = ls[n];
        l += __shfl_xor(l, 16);
        l += __shfl_xor(l, 32);
        linv[n] = 1.0f / l;
    }

#pragma unroll
    for (int n = 0; n < 2; n++) {
        int s = q0 + wid * 32 + n * 16 + l15;
        unsigned short* orow = Ob + ((size_t)b * SEQ + s) * DIMN + h * HD + quad * 4;
#pragma unroll
        for (int df = 0; df < 4; df++) {
            uint2 w;
            w.x = pack2bf(Oa[df][n][0] * linv[n], Oa[df][n][1] * linv[n]);
            w.y = pack2bf(Oa[df][n][2] * linv[n], Oa[df][n][3] * linv[n]);
            *(uint2*)&orow[df * 16] = w;
        }
    }
}

// ---------------------------------------------------------------- launch
extern "C" void kernel_launch(void* const* d_in, const int* in_sizes, int n_in,
                              void* d_out, int out_size, void* d_ws, size_t ws_size,
                              hipStream_t stream) {
    (void)in_sizes; (void)n_in; (void)out_size; (void)ws_size;
    const float* x  = (const float*)d_in[0];
    const unsigned char* mask = (const unsigned char*)d_in[1];
    const float* q_w = (const float*)d_in[2];
    const float* q_b = (const float*)d_in[3];
    const float* k_w = (const float*)d_in[4];
    const float* k_b = (const float*)d_in[5];
    const float* v_w = (const float*)d_in[6];
    const float* v_b = (const float*)d_in[7];
    const float* o_w = (const float*)d_in[8];
    const float* o_b = (const float*)d_in[9];
    float* out = (float*)d_out;

    char* w = (char*)d_ws;
    unsigned short* xb = (unsigned short*)w;                        // 16 MiB (reused as attn output)
    unsigned short* wq = (unsigned short*)(w + (16u << 20));        // 4 x 2 MiB
    unsigned short* wk = wq + (1u << 20);
    unsigned short* wv = wk + (1u << 20);
    unsigned short* wo = wv + (1u << 20);
    float* cosT = (float*)(w + (24u << 20));                        // 256 KiB
    float* sinT = cosT + SEQ * 32;
    unsigned long long* m64 = (unsigned long long*)(w + (24u << 20) + (1u << 19)); // 1 KiB
    unsigned short* Qb  = (unsigned short*)(w + (25u << 20));       // 3 x 16 MiB
    unsigned short* Kb  = Qb + (8u << 20);
    unsigned short* Vtb = Kb + (8u << 20);
    unsigned short* Ob  = xb;                                       // reuse x's slot

    prologue_kernel<<<dim3(6401), 256, 0, stream>>>(x, q_w, k_w, v_w, o_w,
                                                    xb, wq, wk, wv, wo,
                                                    cosT, sinT, mask, m64);

    gemm_qkvt<<<dim3(24, 64), 256, 0, stream>>>(xb, wq, wk, wv, q_b, k_b, v_b,
                                                Qb, Kb, Vtb, cosT, sinT);

    attn_kernel<<<dim3(1024), 256, 0, stream>>>(Qb, Kb, Vtb, m64, Ob);

    gemm_bt<<<dim3(DIMN / 128, MROWS / 128), 256, 0, stream>>>(Ob, wo, o_b, out);
}

// Round 6
// 281.080 us; speedup vs baseline: 1.6583x; 1.6583x over previous
//
#include <hip/hip_runtime.h>
#include <stdint.h>

#define SEQ   2048
#define BATCH 4
#define NH    16
#define HD    64
#define DIMN  1024
#define MROWS (BATCH*SEQ)   // 8192

typedef __attribute__((ext_vector_type(8)))  short          bf16x8;
typedef __attribute__((ext_vector_type(8)))  unsigned short ushort8;
typedef __attribute__((ext_vector_type(4)))  float          f32x4;
typedef __attribute__((ext_vector_type(16))) float          f32x16;

static __device__ __forceinline__ unsigned short f2bf(float f) {
    unsigned int u = __builtin_bit_cast(unsigned int, f);
    u += 0x7fffu + ((u >> 16) & 1u);          // RNE
    return (unsigned short)(u >> 16);
}
// RNE-ish (round-half-up) pack: 3 ops
static __device__ __forceinline__ unsigned int pack2bf(float lo, float hi) {
    unsigned int a = __builtin_bit_cast(unsigned int, lo) + 0x8000u;
    unsigned int b = __builtin_bit_cast(unsigned int, hi) + 0x8000u;
    return __builtin_amdgcn_perm(b, a, 0x07060302u);
}
// truncating pack: 1 op (P in [0,1], rel err <= 2^-8, fine for softmax weights)
static __device__ __forceinline__ unsigned int pack2bf_trunc(float lo, float hi) {
    return __builtin_amdgcn_perm(__builtin_bit_cast(unsigned int, hi),
                                 __builtin_bit_cast(unsigned int, lo), 0x07060302u);
}

// ---------------------------------------------------------------- fused prologue
__global__ __launch_bounds__(256) void prologue_kernel(
        const float* __restrict__ x,
        const float* __restrict__ qw, const float* __restrict__ kw,
        const float* __restrict__ vw, const float* __restrict__ ow,
        unsigned short* __restrict__ xb,
        unsigned short* __restrict__ wq, unsigned short* __restrict__ wk,
        unsigned short* __restrict__ wv, unsigned short* __restrict__ wo,
        float* __restrict__ cosT, float* __restrict__ sinT,
        const unsigned char* __restrict__ mask, unsigned long long* __restrict__ m64) {
    const int bx = blockIdx.x, tid = threadIdx.x;
    if (bx < 4096 + 2048) {
        const float* s; unsigned short* d; int i;
        if (bx < 4096) { s = x; d = xb; i = bx * 2048 + tid * 8; }
        else {
            int wb = bx - 4096;
            int wsel = wb >> 9;
            s = wsel == 0 ? qw : (wsel == 1 ? kw : (wsel == 2 ? vw : ow));
            d = wsel == 0 ? wq : (wsel == 1 ? wk : (wsel == 2 ? wv : wo));
            i = (wb & 511) * 2048 + tid * 8;
        }
        float4 a = *(const float4*)(s + i);
        float4 b = *(const float4*)(s + i + 4);
        ushort8 o;
        o[0]=f2bf(a.x); o[1]=f2bf(a.y); o[2]=f2bf(a.z); o[3]=f2bf(a.w);
        o[4]=f2bf(b.x); o[5]=f2bf(b.y); o[6]=f2bf(b.z); o[7]=f2bf(b.w);
        *(ushort8*)(d + i) = o;
    } else if (bx < 6400) {
        int idx = (bx - 6144) * 256 + tid;        // SEQ*32
        int s = idx >> 5, j = idx & 31;
        float t = (float)(2 * j) / 64.0f;
        float freq = 1.0f / powf(10000.0f, t);
        float ang  = (float)s * freq;
        cosT[idx] = cosf(ang);
        sinT[idx] = sinf(ang);
    } else {
        if (tid < 128) {
            int b = tid >> 5, kt = tid & 31;
            const unsigned char* p = mask + b * SEQ + kt * 64;
            unsigned long long v = 0;
            for (int j = 0; j < 64; j++) v |= (unsigned long long)(p[j] != 0) << j;
            m64[tid] = v;
        }
    }
}

// ---------------------------------------------------------------- fused Q,K,V^T GEMM
// v3 (kept from R4): LDS double-buffer + early stage; ONE barrier per 32-step.
// Chunk XOR swizzle keeps SQ_LDS_BANK_CONFLICT at 0.
__global__ __launch_bounds__(256) void gemm_qkvt(const unsigned short* __restrict__ X,
        const unsigned short* __restrict__ Wq, const unsigned short* __restrict__ Wk,
        const unsigned short* __restrict__ Wv,
        const float* __restrict__ bq, const float* __restrict__ bk, const float* __restrict__ bv,
        unsigned short* __restrict__ Qo, unsigned short* __restrict__ Ko, unsigned short* __restrict__ Vto,
        const float* __restrict__ cosT, const float* __restrict__ sinT) {
    __shared__ __align__(16) unsigned short As0[128 * 32];
    __shared__ __align__(16) unsigned short Bs0[128 * 32];
    __shared__ __align__(16) unsigned short As1[128 * 32];
    __shared__ __align__(16) unsigned short Bs1[128 * 32];
    const int which = blockIdx.x >> 3;
    const int tid  = threadIdx.x;
    const int wid  = tid >> 6, lane = tid & 63;
    const int quad = lane >> 4, l15 = lane & 15;
    const int wm   = wid >> 1,  wn  = wid & 1;

    const unsigned short *Ag, *Bg;
    int m0, n0;
    if (which < 2) {
        m0 = blockIdx.y * 128;                 // token rows
        n0 = (blockIdx.x & 7) * 128;           // embed cols
        Ag = X;  Bg = which == 0 ? Wq : Wk;
    } else {
        m0 = (blockIdx.x & 7) * 128;           // e rows
        n0 = blockIdx.y * 128;                 // token rows
        Ag = Wv; Bg = X;
    }

    f32x4 acc[4][4];
#pragma unroll
    for (int i = 0; i < 4; i++)
#pragma unroll
        for (int j = 0; j < 4; j++) acc[i][j] = (f32x4)0.0f;

    const int rb = wid * 32 + (lane >> 2);
    const int cb = (((lane & 3) ^ ((lane >> 3) & 3)) * 8);
    const int rq = (quad ^ ((l15 >> 1) & 3)) * 8;

#define GSTAGE(BA, BB, KK) do {                                                             \
    _Pragma("unroll")                                                                       \
    for (int i_ = 0; i_ < 2; i_++) {                                                        \
        const unsigned short* ga_ = Ag + (size_t)(m0 + rb + i_ * 16) * DIMN + (KK) + cb;    \
        __builtin_amdgcn_global_load_lds((const __attribute__((address_space(1))) void*)ga_,\
            (__attribute__((address_space(3))) void*)&BA[(wid * 32 + i_ * 16) * 32], 16, 0, 0);\
        const unsigned short* gb_ = Bg + (size_t)(n0 + rb + i_ * 16) * DIMN + (KK) + cb;    \
        __builtin_amdgcn_global_load_lds((const __attribute__((address_space(1))) void*)gb_,\
            (__attribute__((address_space(3))) void*)&BB[(wid * 32 + i_ * 16) * 32], 16, 0, 0);\
    } } while (0)

#define GCOMP(BA, BB) do {                                                                  \
    bf16x8 af_[4], bf_[4];                                                                  \
    _Pragma("unroll")                                                                       \
    for (int f_ = 0; f_ < 4; f_++) af_[f_] = *(const bf16x8*)&BA[(wm * 64 + f_ * 16 + l15) * 32 + rq]; \
    _Pragma("unroll")                                                                       \
    for (int f_ = 0; f_ < 4; f_++) bf_[f_] = *(const bf16x8*)&BB[(wn * 64 + f_ * 16 + l15) * 32 + rq]; \
    _Pragma("unroll")                                                                       \
    for (int fm_ = 0; fm_ < 4; fm_++)                                                       \
        _Pragma("unroll")                                                                   \
        for (int fn_ = 0; fn_ < 4; fn_++)                                                   \
            acc[fm_][fn_] = __builtin_amdgcn_mfma_f32_16x16x32_bf16(af_[fm_], bf_[fn_], acc[fm_][fn_], 0, 0, 0); \
    } while (0)

    GSTAGE(As0, Bs0, 0);
    for (int k0 = 0; k0 < DIMN; k0 += 64) {
        __syncthreads();                           // As0/Bs0 ready
        GSTAGE(As1, Bs1, k0 + 32);                 // issue next into other buffer
        GCOMP(As0, Bs0);
        __syncthreads();                           // As1/Bs1 ready
        if (k0 + 64 < DIMN) GSTAGE(As0, Bs0, k0 + 64);
        GCOMP(As1, Bs1);
    }

    if (which < 2) {                            // Q or K: +bias, scale, RoPE, [B,H,S,D]
        const float* bias   = which == 0 ? bq : bk;
        unsigned short* Out = which == 0 ? Qo : Ko;
        const float scale = which == 0 ? 0.18033688011112042f : 1.0f;  // 0.125*log2e
        float bv4[4];
#pragma unroll
        for (int fn = 0; fn < 4; fn++) bv4[fn] = bias[n0 + wn * 64 + fn * 16 + l15];
        const int h = (n0 >> 6) + wn;
#pragma unroll
        for (int fm = 0; fm < 4; fm++)
#pragma unroll
            for (int r = 0; r < 4; r++) {
                int mrow = m0 + wm * 64 + fm * 16 + quad * 4 + r;
                int b = mrow >> 11, s = mrow & (SEQ - 1);
                unsigned short* orow = Out + ((size_t)(b * NH + h) * SEQ + s) * HD;
                float v0 = (acc[fm][0][r] + bv4[0]) * scale;
                float v1 = (acc[fm][1][r] + bv4[1]) * scale;
                float v2 = (acc[fm][2][r] + bv4[2]) * scale;
                float v3 = (acc[fm][3][r] + bv4[3]) * scale;
                int d0 = l15, d1 = 16 + l15;
                float c0 = cosT[s * 32 + d0], s0 = sinT[s * 32 + d0];
                float c1 = cosT[s * 32 + d1], s1 = sinT[s * 32 + d1];
                orow[d0]      = f2bf(v0 * c0 - v2 * s0);
                orow[d0 + 32] = f2bf(v0 * s0 + v2 * c0);
                orow[d1]      = f2bf(v1 * c1 - v3 * s1);
                orow[d1 + 32] = f2bf(v1 * s1 + v3 * c1);
            }
    } else {                                    // V^T: [B,H,D,S]
        float4 bb[4];
#pragma unroll
        for (int fm = 0; fm < 4; fm++)
            bb[fm] = *(const float4*)&bv[m0 + wm * 64 + fm * 16 + quad * 4];
        const int b     = n0 >> 11;
        const int sbase = (n0 & (SEQ - 1)) + wn * 64 + l15;
#pragma unroll
        for (int fm = 0; fm < 4; fm++)
#pragma unroll
            for (int r = 0; r < 4; r++) {
                int e = m0 + wm * 64 + fm * 16 + quad * 4 + r;
                float bval = r == 0 ? bb[fm].x : (r == 1 ? bb[fm].y : (r == 2 ? bb[fm].z : bb[fm].w));
                unsigned short* row = Vto + ((size_t)(b * NH + (e >> 6)) * HD + (e & 63)) * SEQ + sbase;
#pragma unroll
                for (int fn = 0; fn < 4; fn++)
                    row[fn * 16] = f2bf(acc[fm][fn][r] + bval);
            }
    }
#undef GSTAGE
#undef GCOMP
}

// ---------------------------------------------------------------- output-proj GEMM (fp32 out)
__global__ __launch_bounds__(256) void gemm_bt(const unsigned short* __restrict__ A,
                                               const unsigned short* __restrict__ W,
                                               const float* __restrict__ bias,
                                               float* __restrict__ out) {
    __shared__ __align__(16) unsigned short As0[128 * 32];
    __shared__ __align__(16) unsigned short Bs0[128 * 32];
    __shared__ __align__(16) unsigned short As1[128 * 32];
    __shared__ __align__(16) unsigned short Bs1[128 * 32];
    const int tid  = threadIdx.x;
    const int wid  = tid >> 6, lane = tid & 63;
    const int quad = lane >> 4, l15 = lane & 15;
    const int wm   = wid >> 1,  wn  = wid & 1;
    const int m0   = blockIdx.y * 128, n0 = blockIdx.x * 128;

    f32x4 acc[4][4];
#pragma unroll
    for (int i = 0; i < 4; i++)
#pragma unroll
        for (int j = 0; j < 4; j++) acc[i][j] = (f32x4)0.0f;

    const int rb = wid * 32 + (lane >> 2);
    const int cb = (((lane & 3) ^ ((lane >> 3) & 3)) * 8);
    const int rq = (quad ^ ((l15 >> 1) & 3)) * 8;

#define GSTAGE(BA, BB, KK) do {                                                             \
    _Pragma("unroll")                                                                       \
    for (int i_ = 0; i_ < 2; i_++) {                                                        \
        const unsigned short* ga_ = A + (size_t)(m0 + rb + i_ * 16) * DIMN + (KK) + cb;     \
        __builtin_amdgcn_global_load_lds((const __attribute__((address_space(1))) void*)ga_,\
            (__attribute__((address_space(3))) void*)&BA[(wid * 32 + i_ * 16) * 32], 16, 0, 0);\
        const unsigned short* gb_ = W + (size_t)(n0 + rb + i_ * 16) * DIMN + (KK) + cb;     \
        __builtin_amdgcn_global_load_lds((const __attribute__((address_space(1))) void*)gb_,\
            (__attribute__((address_space(3))) void*)&BB[(wid * 32 + i_ * 16) * 32], 16, 0, 0);\
    } } while (0)

#define GCOMP(BA, BB) do {                                                                  \
    bf16x8 af_[4], bf_[4];                                                                  \
    _Pragma("unroll")                                                                       \
    for (int f_ = 0; f_ < 4; f_++) af_[f_] = *(const bf16x8*)&BA[(wm * 64 + f_ * 16 + l15) * 32 + rq]; \
    _Pragma("unroll")                                                                       \
    for (int f_ = 0; f_ < 4; f_++) bf_[f_] = *(const bf16x8*)&BB[(wn * 64 + f_ * 16 + l15) * 32 + rq]; \
    _Pragma("unroll")                                                                       \
    for (int fm_ = 0; fm_ < 4; fm_++)                                                       \
        _Pragma("unroll")                                                                   \
        for (int fn_ = 0; fn_ < 4; fn_++)                                                   \
            acc[fm_][fn_] = __builtin_amdgcn_mfma_f32_16x16x32_bf16(af_[fm_], bf_[fn_], acc[fm_][fn_], 0, 0, 0); \
    } while (0)

    GSTAGE(As0, Bs0, 0);
    for (int k0 = 0; k0 < DIMN; k0 += 64) {
        __syncthreads();
        GSTAGE(As1, Bs1, k0 + 32);
        GCOMP(As0, Bs0);
        __syncthreads();
        if (k0 + 64 < DIMN) GSTAGE(As0, Bs0, k0 + 64);
        GCOMP(As1, Bs1);
    }

    float bv4[4];
#pragma unroll
    for (int fn = 0; fn < 4; fn++) bv4[fn] = bias[n0 + wn * 64 + fn * 16 + l15];
#pragma unroll
    for (int fm = 0; fm < 4; fm++)
#pragma unroll
        for (int r = 0; r < 4; r++) {
            int mrow = m0 + wm * 64 + fm * 16 + quad * 4 + r;
            float* orow = out + (size_t)mrow * DIMN + n0 + wn * 64;
#pragma unroll
            for (int fn = 0; fn < 4; fn++) orow[fn * 16 + l15] = acc[fm][fn][r] + bv4[fn];
        }
#undef GSTAGE
#undef GCOMP
}

// ---------------------------------------------------------------- flash attention v13
// v12 post-mortem: dropping LDS staging killed the 4-way intra-block dedup ->
// latency collapse (MfmaUtil 9.5%). v13 = v9's PROVEN staging/barrier skeleton
// (single-buffered K/V tiles, 2 barriers/tile, 4 loads/wave/tile) with the
// compute core moved to 32x32x16 MFMA:
//  - QK^T: A=K[32x16], B=Q[16x32] -> st C-layout col=q(lane&31),
//    row=kk=(r&3)+8*(r>>2)+4*hi. 4 chained MFMAs per 32-key half.
//  - P redistribution to the PV B-operand needs only a lane<->lane^32 word
//    exchange (T12 mechanism): 8 packs (already paid) + 4 shfl_xor(32) per
//    half. The Ps LDS buffer, its write->read hazard chain, and 8 DS ops per
//    half are GONE.
//  - PV: A=V^T[32d x 16keys], B=P. 4 MFMAs per half into f32x16 Oa[2].
// LDS = K/V tiles [64][64] shorts (16 KiB), rows 128B, granule-XOR swizzle
// (g ^= row&7) applied on BOTH stage-source and reads (rule 21) -> <=2-way.
__global__ __launch_bounds__(256, 4) void attn_kernel(const unsigned short* __restrict__ Q,
                                                      const unsigned short* __restrict__ K,
                                                      const unsigned short* __restrict__ Vt,
                                                      const unsigned long long* __restrict__ M64,
                                                      unsigned short* __restrict__ Ob) {
    __shared__ __align__(16) unsigned short Kls[64 * 64];   // 8 KiB [token][k]
    __shared__ __align__(16) unsigned short Vls[64 * 64];   // 8 KiB [d][token]

    const int tid  = threadIdx.x;
    const int wid  = tid >> 6, lane = tid & 63;
    const int hi   = lane >> 5, l31 = lane & 31, l7 = lane & 7;
    // XCD-aware swizzle: xcd = bid&7; each XCD owns 8 complete (b,h) groups.
    const int bid = blockIdx.x;
    const int bh  = (bid & 7) * 8 + (bid >> 7);
    const int qt  = (bid >> 3) & 15;
    const int b = bh >> 4, h = bh & 15;
    const int q0 = qt * 128;

    // persistent Q fragments (B-operand): q = q0 + wid*32 + l31,
    // k = ksub*16 + hi*8 + e
    bf16x8 qB[4];
    {
        const unsigned short* qrow = Q + ((size_t)bh * SEQ + q0 + wid * 32 + l31) * HD + hi * 8;
#pragma unroll
        for (int ks = 0; ks < 4; ks++)
            qB[ks] = __builtin_bit_cast(bf16x8, *(const uint4*)(qrow + ks * 16));
    }

    f32x16 Oa[2];                 // O^T tiles: d = dt*32 + (r&3)+8*(r>>2)+4*hi, q = l31
    Oa[0] = (f32x16)0.0f;
    Oa[1] = (f32x16)0.0f;
    float ls = 0.0f;

    const unsigned long long* Mrow = M64 + b * (SEQ / 64);

    // staging bases: each wave stages rows [wid*16, wid*16+16) of both tiles,
    // as 2 loads of 8 rows; lane -> row+=(lane>>3), source granule pre-swizzled
    const int srow = lane >> 3;                          // 0..7
    const int sgr  = ((lane & 7) ^ ((lane >> 3) & 7)) * 8;   // swizzled 16B granule
    const unsigned short* Kg = K  + (size_t)bh * SEQ * HD;
    const unsigned short* Vg = Vt + (size_t)bh * HD * SEQ;
    const unsigned short* Kb0 = Kg + (size_t)(wid * 16 + srow) * HD + sgr;   // + k0*HD + j*8*HD
    const unsigned short* Vb0 = Vg + (size_t)(wid * 16 + srow) * SEQ + sgr;  // + k0 + j*8*SEQ

    for (int kt = 0; kt < SEQ / 64; kt++) {
        const int k0 = kt * 64;
#pragma unroll
        for (int j = 0; j < 2; j++) {
            __builtin_amdgcn_global_load_lds(
                (const __attribute__((address_space(1))) void*)(Kb0 + (size_t)(k0 + j * 8) * HD),
                (__attribute__((address_space(3))) void*)&Kls[(wid * 16 + j * 8) * 64], 16, 0, 0);
            __builtin_amdgcn_global_load_lds(
                (const __attribute__((address_space(1))) void*)(Vb0 + (size_t)(j * 8) * SEQ + k0),
                (__attribute__((address_space(3))) void*)&Vls[(wid * 16 + j * 8) * 64], 16, 0, 0);
        }
        unsigned long long mb = Mrow[kt];
        __syncthreads();                 // drains vmcnt: tiles visible to all waves

#pragma unroll
        for (int h2 = 0; h2 < 2; h2++) {          // 32-key half
            // K fragments: row = h2*32 + l31, k-granule (ksub*2+hi) ^ swizzle
            bf16x8 kA[4];
#pragma unroll
            for (int ks = 0; ks < 4; ks++)
                kA[ks] = *(const bf16x8*)&Kls[(h2 * 32 + l31) * 64 + (((ks << 1) + hi) ^ l7) * 8];

            f32x16 st = (f32x16)0.0f;
            __builtin_amdgcn_s_setprio(1);
#pragma unroll
            for (int ks = 0; ks < 4; ks++)
                st = __builtin_amdgcn_mfma_f32_32x32x16_bf16(kA[ks], qB[ks], st, 0, 0, 0);
            __builtin_amdgcn_s_setprio(0);

            unsigned int mh = (unsigned int)(mb >> (h2 * 32));
            if (mh) {                         // wave-uniform; rare
#pragma unroll
                for (int r = 0; r < 16; r++) {
                    int kk = (r & 3) + ((r >> 2) << 3) + (hi << 2);
                    if ((mh >> kk) & 1u) st[r] = -1e9f;
                }
            }

            // softmax in exp2 domain + row-sum
            float p[16];
#pragma unroll
            for (int r = 0; r < 16; r++) p[r] = __builtin_amdgcn_exp2f(st[r]);
            float s01 = (p[0] + p[1]) + (p[2] + p[3]);
            float s23 = (p[4] + p[5]) + (p[6] + p[7]);
            float s45 = (p[8] + p[9]) + (p[10] + p[11]);
            float s67 = (p[12] + p[13]) + (p[14] + p[15]);
            ls += (s01 + s23) + (s45 + s67);

            // pack to bf16 words: w[ks][dhi][j] covers kk = ks*16+dhi*8+4*hi+2j..+1
            unsigned int w000 = pack2bf_trunc(p[0],  p[1]);
            unsigned int w001 = pack2bf_trunc(p[2],  p[3]);
            unsigned int w010 = pack2bf_trunc(p[4],  p[5]);
            unsigned int w011 = pack2bf_trunc(p[6],  p[7]);
            unsigned int w100 = pack2bf_trunc(p[8],  p[9]);
            unsigned int w101 = pack2bf_trunc(p[10], p[11]);
            unsigned int w110 = pack2bf_trunc(p[12], p[13]);
            unsigned int w111 = pack2bf_trunc(p[14], p[15]);

            // build PV B-operand: lane (q=l31, hi) chunk ks needs keys
            // ks*16 + hi*8 + e.  e-low half from the hi'=0 lane, e-high from
            // hi'=1 lane; both with dhi = dest hi.  One lane^32 exchange.
            bf16x8 pB[2];
#pragma unroll
            for (int ks = 0; ks < 2; ks++) {
                unsigned int own0 = ks == 0 ? (hi ? w010 : w000) : (hi ? w110 : w100);
                unsigned int own1 = ks == 0 ? (hi ? w011 : w001) : (hi ? w111 : w101);
                unsigned int oth0 = ks == 0 ? (hi ? w000 : w010) : (hi ? w100 : w110);
                unsigned int oth1 = ks == 0 ? (hi ? w001 : w011) : (hi ? w101 : w111);
                unsigned int r0 = (unsigned int)__shfl_xor((int)oth0, 32);
                unsigned int r1 = (unsigned int)__shfl_xor((int)oth1, 32);
                uint4 pw;
                pw.x = hi ? r0 : own0;
                pw.y = hi ? r1 : own1;
                pw.z = hi ? own0 : r0;
                pw.w = hi ? own1 : r1;
                pB[ks] = __builtin_bit_cast(bf16x8, pw);
            }

            // PV: V^T fragments row = dt*32 + l31, key-granule swizzled
            __builtin_amdgcn_s_setprio(1);
#pragma unroll
            for (int dt = 0; dt < 2; dt++)
#pragma unroll
                for (int kv = 0; kv < 2; kv++) {
                    bf16x8 vA = *(const bf16x8*)&Vls[(dt * 32 + l31) * 64 +
                                    (((h2 << 2) + (kv << 1) + hi) ^ l7) * 8];
                    Oa[dt] = __builtin_amdgcn_mfma_f32_32x32x16_bf16(vA, pB[kv], Oa[dt], 0, 0, 0);
                }
            __builtin_amdgcn_s_setprio(0);
        }
        __syncthreads();                 // before next tile overwrites tiles
    }

    float lsum = ls + __shfl_xor(ls, 32);
    float linv = 1.0f / lsum;

    const int s = q0 + wid * 32 + l31;
    unsigned short* orow = Ob + ((size_t)b * SEQ + s) * DIMN + h * HD + hi * 4;
#pragma unroll
    for (int dt = 0; dt < 2; dt++)
#pragma unroll
        for (int rq = 0; rq < 4; rq++) {
            uint2 w;
            w.x = pack2bf(Oa[dt][rq * 4 + 0] * linv, Oa[dt][rq * 4 + 1] * linv);
            w.y = pack2bf(Oa[dt][rq * 4 + 2] * linv, Oa[dt][rq * 4 + 3] * linv);
            *(uint2*)&orow[dt * 32 + rq * 8] = w;
        }
}

// ---------------------------------------------------------------- launch
extern "C" void kernel_launch(void* const* d_in, const int* in_sizes, int n_in,
                              void* d_out, int out_size, void* d_ws, size_t ws_size,
                              hipStream_t stream) {
    (void)in_sizes; (void)n_in; (void)out_size; (void)ws_size;
    const float* x  = (const float*)d_in[0];
    const unsigned char* mask = (const unsigned char*)d_in[1];
    const float* q_w = (const float*)d_in[2];
    const float* q_b = (const float*)d_in[3];
    const float* k_w = (const float*)d_in[4];
    const float* k_b = (const float*)d_in[5];
    const float* v_w = (const float*)d_in[6];
    const float* v_b = (const float*)d_in[7];
    const float* o_w = (const float*)d_in[8];
    const float* o_b = (const float*)d_in[9];
    float* out = (float*)d_out;

    char* w = (char*)d_ws;
    unsigned short* xb = (unsigned short*)w;                        // 16 MiB (reused as attn output)
    unsigned short* wq = (unsigned short*)(w + (16u << 20));        // 4 x 2 MiB
    unsigned short* wk = wq + (1u << 20);
    unsigned short* wv = wk + (1u << 20);
    unsigned short* wo = wv + (1u << 20);
    float* cosT = (float*)(w + (24u << 20));                        // 256 KiB
    float* sinT = cosT + SEQ * 32;
    unsigned long long* m64 = (unsigned long long*)(w + (24u << 20) + (1u << 19)); // 1 KiB
    unsigned short* Qb  = (unsigned short*)(w + (25u << 20));       // 3 x 16 MiB
    unsigned short* Kb  = Qb + (8u << 20);
    unsigned short* Vtb = Kb + (8u << 20);
    unsigned short* Ob  = xb;                                       // reuse x's slot

    prologue_kernel<<<dim3(6401), 256, 0, stream>>>(x, q_w, k_w, v_w, o_w,
                                                    xb, wq, wk, wv, wo,
                                                    cosT, sinT, mask, m64);

    gemm_qkvt<<<dim3(24, 64), 256, 0, stream>>>(xb, wq, wk, wv, q_b, k_b, v_b,
                                                Qb, Kb, Vtb, cosT, sinT);

    attn_kernel<<<dim3(1024), 256, 0, stream>>>(Qb, Kb, Vtb, m64, Ob);

    gemm_bt<<<dim3(DIMN / 128, MROWS / 128), 256, 0, stream>>>(Ob, wo, o_b, out);
}